// Round 6
// baseline (60.054 us; speedup 1.0000x reference)
//
#include <hip/hip_runtime.h>

#define LL 197
#define NN 128
#define DD 768
#define TT 16
#define PP 196
#define NSL 98                    // p-slices per b, 2 p each
#define SCL 0.03608439182435161f  // 1/sqrt(768)

typedef short short8 __attribute__((ext_vector_type(8)));
typedef float f32x4 __attribute__((ext_vector_type(4)));

static __device__ __forceinline__ ushort f2bf(float f) {
    union { float f; unsigned int u; } a; a.f = f;
    unsigned int r = a.u + 0x7fffu + ((a.u >> 16) & 1u);
    return (ushort)(r >> 16);
}
static __device__ __forceinline__ float bf2f(ushort u) {
    union { unsigned int u; float f; } c; c.u = (unsigned int)u << 16; return c.f;
}

// Swizzled LDS index for the 32x768 bf16 V tile: 16B-block XOR on row low bits.
static __device__ __forceinline__ int vidx(int r, int d) {
    return r * DD + ((((d >> 3) ^ (r & 7)) << 3) | (d & 7));
}

// ---------------- K0: LayerNorm of the 128 cls rows -> qn bf16 ----------------
__global__ __launch_bounds__(256) void k_lnq(const float* __restrict__ x,
                                             const float* __restrict__ gamma,
                                             const float* __restrict__ beta,
                                             ushort* __restrict__ qn) {
    int row  = (blockIdx.x << 2) + (threadIdx.x >> 6);   // 0..127
    int lane = threadIdx.x & 63;
    const float4* xr = (const float4*)(x + (size_t)row * DD);
    float4 v[3];
    float s = 0.f, ss = 0.f;
#pragma unroll
    for (int j = 0; j < 3; ++j) {
        v[j] = xr[lane + 64 * j];
        s  += v[j].x + v[j].y + v[j].z + v[j].w;
        ss = fmaf(v[j].x, v[j].x, ss); ss = fmaf(v[j].y, v[j].y, ss);
        ss = fmaf(v[j].z, v[j].z, ss); ss = fmaf(v[j].w, v[j].w, ss);
    }
#pragma unroll
    for (int o = 32; o > 0; o >>= 1) { s += __shfl_xor(s, o); ss += __shfl_xor(ss, o); }
    float mu  = s * (1.f / DD);
    float var = fmaf(ss, 1.f / DD, -mu * mu);
    float rs  = rsqrtf(var + 1e-5f);
    const float4* g4 = (const float4*)gamma;
    const float4* b4 = (const float4*)beta;
    ushort4* outr = (ushort4*)(qn + (size_t)row * DD);
#pragma unroll
    for (int j = 0; j < 3; ++j) {
        int i4 = lane + 64 * j;
        float4 g = g4[i4], b = b4[i4];
        ushort4 o4;
        o4.x = f2bf((v[j].x - mu) * rs * g.x + b.x);
        o4.y = f2bf((v[j].y - mu) * rs * g.y + b.y);
        o4.z = f2bf((v[j].z - mu) * rs * g.z + b.z);
        o4.w = f2bf((v[j].w - mu) * rs * g.w + b.w);
        outr[i4] = o4;
    }
}

// ------- K1: fused value-row LN + banded attention via MFMA -------
// Block = (b, sl). Tile rows r=0..31 map to x[1 + sl*2 + (r>>4), b*16 + (r&15)].
// Stage: pass1 fp32 stats (8 lanes per row, shfl reduce), pass2 normalize->bf16
// into swizzled Vl. mm1: S = Q.V^T (K split over wave pairs). W = band-masked
// sigmoid-0.5. mm2: feat += W.V. Partials bf16 per slice.
template<bool USE_PART>
__global__ __launch_bounds__(256, 3) void k_attn(const float* __restrict__ x,
                                                 const float* __restrict__ gamma,
                                                 const float* __restrict__ beta,
                                                 const ushort* __restrict__ qn,
                                                 ushort* __restrict__ part,
                                                 float* __restrict__ outp) {
    __shared__ ushort Vl[32 * DD];     // 49152 B
    __shared__ float  Sl[2][TT][32];   // 4096 B
    __shared__ ushort Wl[TT * 32];     // 1024 B, A-frag order

    int gid = blockIdx.x;
    int b = gid / NSL, sl = gid % NSL;
    int w   = threadIdx.x >> 6, l = threadIdx.x & 63;
    int wq  = w & 1, kh = w >> 1;
    int l15 = l & 15, lh = l >> 4;

    // q fragments in registers (A of mm1): 12 x short8
    const ushort* qbase = qn + (size_t)(b * TT + l15) * DD;
    short8 qf[12];
#pragma unroll
    for (int s = 0; s < 12; ++s)
        qf[s] = *(const short8*)(qbase + kh * 384 + s * 32 + lh * 8);

    // ---- staging role: row r owned by 8 lanes j ----
    int r = threadIdx.x >> 3, j = threadIdx.x & 7;
    const float* vrow =
        x + ((size_t)(1 + sl * 2 + (r >> 4)) * NN + b * TT + (r & 15)) * DD;

    // pass1: row stats
    float s1 = 0.f, s2 = 0.f;
#pragma unroll
    for (int cc = 0; cc < 12; ++cc) {
        int d0 = (cc * 8 + j) * 8;
        float4 a = *(const float4*)(vrow + d0);
        float4 c = *(const float4*)(vrow + d0 + 4);
        s1 += a.x + a.y + a.z + a.w + c.x + c.y + c.z + c.w;
        s2 = fmaf(a.x, a.x, s2); s2 = fmaf(a.y, a.y, s2);
        s2 = fmaf(a.z, a.z, s2); s2 = fmaf(a.w, a.w, s2);
        s2 = fmaf(c.x, c.x, s2); s2 = fmaf(c.y, c.y, s2);
        s2 = fmaf(c.z, c.z, s2); s2 = fmaf(c.w, c.w, s2);
    }
#pragma unroll
    for (int o = 1; o < 8; o <<= 1) { s1 += __shfl_xor(s1, o); s2 += __shfl_xor(s2, o); }
    float mu  = s1 * (1.f / DD);
    float var = fmaf(s2, 1.f / DD, -mu * mu);
    float rs  = rsqrtf(var + 1e-5f);

    // pass2: normalize + pack + stage (loads are L2-hot)
    const float4* g4 = (const float4*)gamma;
    const float4* b4 = (const float4*)beta;
#pragma unroll
    for (int cc = 0; cc < 12; ++cc) {
        int c8 = cc * 8 + j;
        int d0 = c8 * 8;
        float4 a = *(const float4*)(vrow + d0);
        float4 c = *(const float4*)(vrow + d0 + 4);
        float4 g0 = g4[c8 * 2], g1 = g4[c8 * 2 + 1];
        float4 e0 = b4[c8 * 2], e1 = b4[c8 * 2 + 1];
        union { ushort sv[8]; short8 v; } u;
        u.sv[0] = f2bf((a.x - mu) * rs * g0.x + e0.x);
        u.sv[1] = f2bf((a.y - mu) * rs * g0.y + e0.y);
        u.sv[2] = f2bf((a.z - mu) * rs * g0.z + e0.z);
        u.sv[3] = f2bf((a.w - mu) * rs * g0.w + e0.w);
        u.sv[4] = f2bf((c.x - mu) * rs * g1.x + e1.x);
        u.sv[5] = f2bf((c.y - mu) * rs * g1.y + e1.y);
        u.sv[6] = f2bf((c.z - mu) * rs * g1.z + e1.z);
        u.sv[7] = f2bf((c.w - mu) * rs * g1.w + e1.w);
        *(short8*)&Vl[vidx(r, d0)] = u.v;
    }
    __syncthreads();

    // ---- mm1: partial S over this wave's k-half ----
    f32x4 sacc = (f32x4){0.f, 0.f, 0.f, 0.f};
    int vr = wq * 16 + l15;
#pragma unroll
    for (int s = 0; s < 12; ++s) {
        int k0 = kh * 384 + s * 32 + lh * 8;
        short8 bfr = *(const short8*)&Vl[vidx(vr, k0)];
        sacc = __builtin_amdgcn_mfma_f32_16x16x32_bf16(qf[s], bfr, sacc, 0, 0, 0);
    }
#pragma unroll
    for (int q = 0; q < 4; ++q) Sl[kh][lh * 4 + q][wq * 16 + l15] = sacc[q];
    __syncthreads();

    // ---- W = band-masked sigmoid(S)-0.5, packed in A-frag order ----
    {
        int t  = threadIdx.x & 15;
        int rr = (threadIdx.x >> 4) * 2;
        float s0 = Sl[0][t][rr]     + Sl[1][t][rr];
        float sx = Sl[0][t][rr + 1] + Sl[1][t][rr + 1];
        int m0 = rr & 15, m1 = (rr + 1) & 15;
        float w0 = (m0 - t <= 2 && t - m0 <= 2)
                     ? (1.f / (1.f + __expf(-s0 * SCL)) - 0.5f) : 0.f;
        float w1 = (m1 - t <= 2 && t - m1 <= 2)
                     ? (1.f / (1.f + __expf(-sx * SCL)) - 0.5f) : 0.f;
        unsigned pk = (unsigned)f2bf(w0) | ((unsigned)f2bf(w1) << 16);
        *(unsigned*)((char*)Wl + (t + (rr >> 3) * 16) * 16 + (rr & 7) * 2) = pk;
    }
    __syncthreads();

    // ---- mm2: feat += W . V (wave owns d-slice [w*192, w*192+192)) ----
    f32x4 acc[12];
    short8 wfrag = *(const short8*)((const char*)Wl + l * 16);
#pragma unroll
    for (int i = 0; i < 12; ++i) {
        int d0 = w * 192 + i * 16;
        union { ushort sv[8]; short8 v; } u;
#pragma unroll
        for (int jj = 0; jj < 8; ++jj)
            u.sv[jj] = Vl[vidx(lh * 8 + jj, d0 + l15)];
        acc[i] = __builtin_amdgcn_mfma_f32_16x16x32_bf16(
            wfrag, u.v, (f32x4){0.f, 0.f, 0.f, 0.f}, 0, 0, 0);
    }

    // ---- epilogue: C/D layout col=l&15, row=(l>>4)*4+q ----
#pragma unroll
    for (int i = 0; i < 12; ++i) {
        int d = w * 192 + i * 16 + l15;
#pragma unroll
        for (int q = 0; q < 4; ++q) {
            int t = lh * 4 + q;
            if (USE_PART) {
                part[((size_t)(sl * 8 + b) * TT + t) * DD + d] = f2bf(acc[i][q]);
            } else {
                atomicAdd(outp + (size_t)(b * TT + t) * DD + d, acc[i][q]);
            }
        }
    }
}

// ---------------- K2: reduce 98 bf16 slice-partials ----------------
__global__ __launch_bounds__(256) void k_reduce(const ushort* __restrict__ part,
                                                float* __restrict__ out) {
    int e8 = (blockIdx.x * 256 + threadIdx.x) * 8;   // elem index over 98304, x8
    float s[8] = {0.f, 0.f, 0.f, 0.f, 0.f, 0.f, 0.f, 0.f};
#pragma unroll 2
    for (int sl = 0; sl < NSL; ++sl) {
        union { short8 v; ushort sv[8]; } u;
        u.v = *(const short8*)(part + (size_t)sl * 8 * TT * DD + e8);
#pragma unroll
        for (int k = 0; k < 8; ++k) s[k] += bf2f(u.sv[k]);
    }
    float4* o4 = (float4*)(out + e8);
    o4[0] = (float4){s[0], s[1], s[2], s[3]};
    o4[1] = (float4){s[4], s[5], s[6], s[7]};
}

__global__ __launch_bounds__(256) void k_zero(float* __restrict__ out) {
    out[blockIdx.x * 256 + threadIdx.x] = 0.f;
}

extern "C" void kernel_launch(void* const* d_in, const int* in_sizes, int n_in,
                              void* d_out, int out_size, void* d_ws, size_t ws_size,
                              hipStream_t stream) {
    const float* x     = (const float*)d_in[0];
    const float* gamma = (const float*)d_in[1];
    const float* beta  = (const float*)d_in[2];
    float* out = (float*)d_out;

    const size_t qn_bytes   = (size_t)NN * DD * 2;                 // 196,608
    const size_t part_bytes = (size_t)NSL * 8 * TT * DD * 2;       // 19,267,584
    ushort* qn   = (ushort*)d_ws;
    ushort* part = (ushort*)((char*)d_ws + qn_bytes);
    bool use_part = ws_size >= qn_bytes + part_bytes;

    k_lnq<<<NN / 4, 256, 0, stream>>>(x, gamma, beta, qn);
    if (use_part) {
        k_attn<true><<<8 * NSL, 256, 0, stream>>>(x, gamma, beta, qn, part, out);
        k_reduce<<<48, 256, 0, stream>>>(part, out);
    } else {
        k_zero<<<NN * DD / 256, 256, 0, stream>>>(out);
        k_attn<false><<<8 * NSL, 256, 0, stream>>>(x, gamma, beta, qn, part, out);
    }
}

// Round 7
// 44.999 us; speedup vs baseline: 1.3345x; 1.3345x over previous
//
#include <hip/hip_runtime.h>

#define LL 197
#define NN 128
#define DD 768
#define TT 16
#define PP 196
#define NSL 49                    // p-slices per b, 4 p each (2 tiles of 2p)
#define SCL 0.03608439182435161f  // 1/sqrt(768)

typedef short short8 __attribute__((ext_vector_type(8)));
typedef float f32x4 __attribute__((ext_vector_type(4)));

static __device__ __forceinline__ ushort f2bf(float f) {
    union { float f; unsigned int u; } a; a.f = f;
    unsigned int r = a.u + 0x7fffu + ((a.u >> 16) & 1u);
    return (ushort)(r >> 16);
}

// Swizzled LDS index for the 32x768 bf16 V tile: 16B-block XOR on row low bits.
static __device__ __forceinline__ int vidx(int r, int d) {
    return r * DD + ((((d >> 3) ^ (r & 7)) << 3) | (d & 7));
}

// ---------------- K0: LayerNorm of the 128 cls rows -> qn bf16 ----------------
__global__ __launch_bounds__(256) void k_lnq(const float* __restrict__ x,
                                             const float* __restrict__ gamma,
                                             const float* __restrict__ beta,
                                             ushort* __restrict__ qn) {
    int row  = (blockIdx.x << 2) + (threadIdx.x >> 6);   // 0..127
    int lane = threadIdx.x & 63;
    const float4* xr = (const float4*)(x + (size_t)row * DD);
    float4 v[3];
    float s = 0.f, ss = 0.f;
#pragma unroll
    for (int j = 0; j < 3; ++j) {
        v[j] = xr[lane + 64 * j];
        s  += v[j].x + v[j].y + v[j].z + v[j].w;
        ss = fmaf(v[j].x, v[j].x, ss); ss = fmaf(v[j].y, v[j].y, ss);
        ss = fmaf(v[j].z, v[j].z, ss); ss = fmaf(v[j].w, v[j].w, ss);
    }
#pragma unroll
    for (int o = 32; o > 0; o >>= 1) { s += __shfl_xor(s, o); ss += __shfl_xor(ss, o); }
    float mu  = s * (1.f / DD);
    float var = fmaf(ss, 1.f / DD, -mu * mu);
    float rs  = rsqrtf(var + 1e-5f);
    const float4* g4 = (const float4*)gamma;
    const float4* b4 = (const float4*)beta;
    ushort4* outr = (ushort4*)(qn + (size_t)row * DD);
#pragma unroll
    for (int j = 0; j < 3; ++j) {
        int i4 = lane + 64 * j;
        float4 g = g4[i4], b = b4[i4];
        ushort4 o4;
        o4.x = f2bf((v[j].x - mu) * rs * g.x + b.x);
        o4.y = f2bf((v[j].y - mu) * rs * g.y + b.y);
        o4.z = f2bf((v[j].z - mu) * rs * g.z + b.z);
        o4.w = f2bf((v[j].w - mu) * rs * g.w + b.w);
        outr[i4] = o4;
    }
}

__global__ __launch_bounds__(256) void k_zero(float* __restrict__ out) {
    out[blockIdx.x * 256 + threadIdx.x] = 0.f;
}

// ------- K1: fused value-row LN (in-register, wave-owned rows) + attention ----
// Block = (b, sl of 4 p) = 2 tiles of 32 rows. Wave w owns tile rows w*8..w*8+7,
// loaded once as fp32 (row spread over 64 lanes, 3 float4/lane), stats via
// 64-lane butterfly (4 rows interleaved), normalized in-reg, packed bf16 into
// swizzled Vl. mm1/W/mm2 identical to the verified R5 kernel. Epilogue:
// fp32 atomicAdd into zeroed out.
__global__ __launch_bounds__(256, 2) void k_attn(const float* __restrict__ x,
                                                 const float* __restrict__ gamma,
                                                 const float* __restrict__ beta,
                                                 const ushort* __restrict__ qn,
                                                 float* __restrict__ outp) {
    __shared__ ushort Vl[32 * DD];     // 49152 B
    __shared__ float  Sl[2][TT][32];   // 4096 B
    __shared__ ushort Wl[TT * 32];     // 1024 B, A-frag order

    int gid = blockIdx.x;
    int b = gid / NSL, sl = gid % NSL;
    int w   = threadIdx.x >> 6, l = threadIdx.x & 63;
    int wq  = w & 1, kh = w >> 1;
    int l15 = l & 15, lh = l >> 4;

    // gamma/beta fragments for this lane's d-slots (d = 4*(l+64k)+x)
    const float4* g4 = (const float4*)gamma;
    const float4* b4 = (const float4*)beta;
    float4 gv[3], bv[3];
#pragma unroll
    for (int k = 0; k < 3; ++k) { gv[k] = g4[l + 64 * k]; bv[k] = b4[l + 64 * k]; }

    // q fragments in registers (A of mm1): 12 x short8, loaded once
    const ushort* qbase = qn + (size_t)(b * TT + l15) * DD;
    short8 qf[12];
#pragma unroll
    for (int s = 0; s < 12; ++s)
        qf[s] = *(const short8*)(qbase + kh * 384 + s * 32 + lh * 8);

    f32x4 acc[12];
#pragma unroll
    for (int i = 0; i < 12; ++i) acc[i] = (f32x4){0.f, 0.f, 0.f, 0.f};

    float4 ldA[4][3], ldB[4][3];

#define GLOAD(LD, TP, G)                                                          \
    _Pragma("unroll")                                                             \
    for (int u = 0; u < 4; ++u) {                                                 \
        int r = w * 8 + (G) * 4 + u;                                              \
        int p = sl * 4 + (TP) * 2 + (r >> 4);                                     \
        const float4* rp =                                                        \
            (const float4*)(x + ((size_t)(1 + p) * NN + b * TT + (r & 15)) * DD); \
        _Pragma("unroll")                                                         \
        for (int k = 0; k < 3; ++k) LD[u][k] = rp[l + 64 * k];                    \
    }

#define LNWRITE(LD, G)                                                            \
    {                                                                             \
        float s1[4], s2[4];                                                       \
        _Pragma("unroll")                                                         \
        for (int u = 0; u < 4; ++u) {                                             \
            s1[u] = 0.f; s2[u] = 0.f;                                             \
            _Pragma("unroll")                                                     \
            for (int k = 0; k < 3; ++k) {                                         \
                float4 c = LD[u][k];                                              \
                s1[u] += c.x + c.y + c.z + c.w;                                   \
                s2[u] = fmaf(c.x, c.x, s2[u]); s2[u] = fmaf(c.y, c.y, s2[u]);     \
                s2[u] = fmaf(c.z, c.z, s2[u]); s2[u] = fmaf(c.w, c.w, s2[u]);     \
            }                                                                     \
        }                                                                         \
        _Pragma("unroll")                                                         \
        for (int o = 32; o > 0; o >>= 1) {                                        \
            _Pragma("unroll")                                                     \
            for (int u = 0; u < 4; ++u) {                                         \
                s1[u] += __shfl_xor(s1[u], o);                                    \
                s2[u] += __shfl_xor(s2[u], o);                                    \
            }                                                                     \
        }                                                                         \
        _Pragma("unroll")                                                         \
        for (int u = 0; u < 4; ++u) {                                             \
            int r = w * 8 + (G) * 4 + u;                                          \
            int r7 = r & 7;                                                       \
            float mu  = s1[u] * (1.f / DD);                                       \
            float var = fmaf(s2[u], 1.f / DD, -mu * mu);                          \
            float rs  = rsqrtf(var + 1e-5f);                                      \
            _Pragma("unroll")                                                     \
            for (int k = 0; k < 3; ++k) {                                         \
                float4 c = LD[u][k];                                              \
                ushort4 ut;                                                       \
                ut.x = f2bf((c.x - mu) * rs * gv[k].x + bv[k].x);                 \
                ut.y = f2bf((c.y - mu) * rs * gv[k].y + bv[k].y);                 \
                ut.z = f2bf((c.z - mu) * rs * gv[k].z + bv[k].z);                 \
                ut.w = f2bf((c.w - mu) * rs * gv[k].w + bv[k].w);                 \
                int blk = (l >> 1) + 32 * k;                                      \
                *(ushort4*)&Vl[r * DD + (((blk ^ r7) << 3) + 4 * (l & 1))] = ut;  \
            }                                                                     \
        }                                                                         \
    }

#define COMPUTE()                                                                 \
    {                                                                             \
        f32x4 sacc = (f32x4){0.f, 0.f, 0.f, 0.f};                                 \
        int vr = wq * 16 + l15;                                                   \
        _Pragma("unroll")                                                         \
        for (int s = 0; s < 12; ++s) {                                            \
            int k0 = kh * 384 + s * 32 + lh * 8;                                  \
            short8 bfr = *(const short8*)&Vl[vidx(vr, k0)];                       \
            sacc = __builtin_amdgcn_mfma_f32_16x16x32_bf16(qf[s], bfr, sacc, 0, 0, 0); \
        }                                                                         \
        _Pragma("unroll")                                                         \
        for (int q = 0; q < 4; ++q) Sl[kh][lh * 4 + q][wq * 16 + l15] = sacc[q];  \
        __syncthreads();                                                          \
        {                                                                         \
            int t  = threadIdx.x & 15;                                            \
            int rr = (threadIdx.x >> 4) * 2;                                      \
            float s0 = Sl[0][t][rr]     + Sl[1][t][rr];                           \
            float sx = Sl[0][t][rr + 1] + Sl[1][t][rr + 1];                       \
            int m0 = rr & 15, m1 = (rr + 1) & 15;                                 \
            float w0 = (m0 - t <= 2 && t - m0 <= 2)                               \
                         ? (1.f / (1.f + __expf(-s0 * SCL)) - 0.5f) : 0.f;        \
            float w1 = (m1 - t <= 2 && t - m1 <= 2)                               \
                         ? (1.f / (1.f + __expf(-sx * SCL)) - 0.5f) : 0.f;        \
            unsigned pk = (unsigned)f2bf(w0) | ((unsigned)f2bf(w1) << 16);        \
            *(unsigned*)((char*)Wl + (t + (rr >> 3) * 16) * 16 + (rr & 7) * 2) = pk; \
        }                                                                         \
        __syncthreads();                                                          \
        short8 wfrag = *(const short8*)((const char*)Wl + l * 16);                \
        _Pragma("unroll")                                                         \
        for (int i = 0; i < 12; ++i) {                                            \
            int d0 = w * 192 + i * 16;                                            \
            union { ushort sv[8]; short8 v; } u;                                  \
            _Pragma("unroll")                                                     \
            for (int jj = 0; jj < 8; ++jj)                                        \
                u.sv[jj] = Vl[vidx(lh * 8 + jj, d0 + l15)];                       \
            acc[i] = __builtin_amdgcn_mfma_f32_16x16x32_bf16(wfrag, u.v, acc[i], 0, 0, 0); \
        }                                                                         \
    }

    // tile 0
    GLOAD(ldA, 0, 0);
    GLOAD(ldB, 0, 1);
    LNWRITE(ldA, 0);
    LNWRITE(ldB, 1);
    __syncthreads();
    GLOAD(ldA, 1, 0);   // prefetch tile-1 rows 0..3 (per wave) during tile-0 compute
    COMPUTE();          // tile 0
    __syncthreads();    // Vl free
    // tile 1
    LNWRITE(ldA, 0);
    GLOAD(ldB, 1, 1);
    LNWRITE(ldB, 1);
    __syncthreads();
    COMPUTE();          // tile 1

#undef GLOAD
#undef LNWRITE
#undef COMPUTE

    // ---- epilogue: C/D layout col=l&15, row=(l>>4)*4+q; fp32 atomics ----
#pragma unroll
    for (int i = 0; i < 12; ++i) {
        int d = w * 192 + i * 16 + l15;
#pragma unroll
        for (int q = 0; q < 4; ++q) {
            int t = lh * 4 + q;
            atomicAdd(outp + (size_t)(b * TT + t) * DD + d, acc[i][q]);
        }
    }
}

extern "C" void kernel_launch(void* const* d_in, const int* in_sizes, int n_in,
                              void* d_out, int out_size, void* d_ws, size_t ws_size,
                              hipStream_t stream) {
    const float* x     = (const float*)d_in[0];
    const float* gamma = (const float*)d_in[1];
    const float* beta  = (const float*)d_in[2];
    float* out = (float*)d_out;
    ushort* qn = (ushort*)d_ws;   // 128*768 bf16 = 196,608 B

    k_zero<<<NN * DD / 256, 256, 0, stream>>>(out);
    k_lnq<<<NN / 4, 256, 0, stream>>>(x, gamma, beta, qn);
    k_attn<<<8 * NSL, 256, 0, stream>>>(x, gamma, beta, qn, out);
}